// Round 9
// baseline (99.977 us; speedup 1.0000x reference)
//
#include <hip/hip_runtime.h>

typedef _Float16 f16;
typedef _Float16 f16x8 __attribute__((ext_vector_type(8)));
typedef _Float16 f16x4 __attribute__((ext_vector_type(4)));
typedef float f32x4 __attribute__((ext_vector_type(4)));

#define MFMA_F16(a, b, c) __builtin_amdgcn_mfma_f32_16x16x32_f16(a, b, c, 0, 0, 0)

__device__ __forceinline__ void gld16(const void* g, void* l) {
  __builtin_amdgcn_global_load_lds(
      (const __attribute__((address_space(1))) unsigned int*)(unsigned long long)g,
      (__attribute__((address_space(3))) unsigned int*)(unsigned long long)l, 16, 0, 0);
}

// ---------------------------------------------------------------- conversions
__global__ __launch_bounds__(256) void cvt_x_kernel(const float* __restrict__ in,
                                                    f16* __restrict__ out, int n8) {
  int i = blockIdx.x * 256 + threadIdx.x;
  if (i >= n8) return;
  const float4* p = (const float4*)(in + (size_t)i * 8);
  float4 a = p[0], b = p[1];
  f16x8 o = {(f16)a.x, (f16)a.y, (f16)a.z, (f16)a.w,
             (f16)b.x, (f16)b.y, (f16)b.z, (f16)b.w};
  *(f16x8*)(out + (size_t)i * 8) = o;
}

__global__ __launch_bounds__(256) void cvt_w4_kernel(const float* __restrict__ w0,
                                                     const float* __restrict__ w1,
                                                     const float* __restrict__ w2,
                                                     const float* __restrict__ w3,
                                                     f16* __restrict__ out) {
  int i = blockIdx.x * 256 + threadIdx.x;
  int t = i >> 17, r = i & 131071;
  const float* w = (t == 0) ? w0 : (t == 1) ? w1 : (t == 2) ? w2 : w3;
  const float4* p = (const float4*)(w + (size_t)r * 8);
  float4 a = p[0], b = p[1];
  f16x8 o = {(f16)a.x, (f16)a.y, (f16)a.z, (f16)a.w,
             (f16)b.x, (f16)b.y, (f16)b.z, (f16)b.w};
  *(f16x8*)(out + (size_t)t * 1048576 + (size_t)r * 8) = o;
}

// -------------------------------------- fused QKV GEMM, 64x128 tile, 2-phase
// 1280 blocks (2x of R5) -> 3 blocks/CU (48KB LDS), smaller tail.
__global__ __launch_bounds__(256) void qkv_gemm_kernel(
    const f16* __restrict__ A, const f16* __restrict__ Wq,
    const f16* __restrict__ Wk, const f16* __restrict__ Wv,
    f16* __restrict__ Qo, f16* __restrict__ Ko, f16* __restrict__ VT) {
  __shared__ __align__(16) f16 As[2][64 * 64];
  __shared__ __align__(16) f16 Bs[2][128 * 64];
  const int bid = blockIdx.x + blockIdx.y * 8;
  const int swz = (bid & 7) * 160 + (bid >> 3);
  const int bx = swz & 7, y = swz >> 3;
  const f16* Bw;
  f16* Co = nullptr;
  int mt, isv = 0;
  if (y < 32) { Bw = Wq; Co = Qo; mt = (y & 15) | ((y >> 4) << 5); }
  else if (y < 96) { Bw = Wk; Co = Ko; mt = y - 32; }
  else { Bw = Wv; isv = 1; mt = y - 96; }
  const int m0 = mt * 64, n0 = bx * 128;
  const int tid = threadIdx.x, lane = tid & 63, w = tid >> 6;
  const int wr = w >> 1, wc = w & 1, g = lane >> 4, c = lane & 15;
  const int r_st = tid >> 3, t_st = tid & 7;

  auto stage = [&](int k0, int buf) {
#pragma unroll
    for (int i = 0; i < 2; ++i) {
      int row = r_st + i * 32;
      int sl = (t_st ^ (row & 7)) * 8;
      gld16(&A[(size_t)(m0 + row) * 1024 + k0 + sl], &As[buf][(row * 8 + t_st) * 8]);
    }
#pragma unroll
    for (int i = 0; i < 4; ++i) {
      int row = r_st + i * 32;
      int sl = (t_st ^ (row & 7)) * 8;
      gld16(&Bw[(size_t)(n0 + row) * 1024 + k0 + sl], &Bs[buf][(row * 8 + t_st) * 8]);
    }
  };

  f32x4 acc[2][4] = {};

  stage(0, 0);
  __syncthreads();

  for (int t = 0; t < 16; ++t) {
    const int cur = t & 1;
    if (t < 15) stage((t + 1) * 64, cur ^ 1);
#pragma unroll
    for (int kb = 0; kb < 2; ++kb) {
      f16x8 af[2], bf[4];
      const int sw = ((kb * 4 + g) ^ (c & 7)) * 8;
#pragma unroll
      for (int m2 = 0; m2 < 2; ++m2)
        af[m2] = *(const f16x8*)&As[cur][(wr * 32 + m2 * 16 + c) * 64 + sw];
#pragma unroll
      for (int nt = 0; nt < 4; ++nt)
        bf[nt] = *(const f16x8*)&Bs[cur][(wc * 64 + nt * 16 + c) * 64 + sw];
#pragma unroll
      for (int m2 = 0; m2 < 2; ++m2)
#pragma unroll
        for (int nt = 0; nt < 4; ++nt)
          acc[m2][nt] = MFMA_F16(af[m2], bf[nt], acc[m2][nt]);
    }
    __syncthreads();
  }

  if (isv) {
    const int b = m0 >> 11;
    const int n_base = (m0 & 2047) + wr * 32 + g * 4;
#pragma unroll
    for (int m2 = 0; m2 < 2; ++m2)
#pragma unroll
      for (int nt = 0; nt < 4; ++nt) {
        int col = n0 + wc * 64 + nt * 16 + c;
        int h = col >> 6, d = col & 63;
        f16x4 pv = {(f16)acc[m2][nt][0], (f16)acc[m2][nt][1],
                    (f16)acc[m2][nt][2], (f16)acc[m2][nt][3]};
        *(f16x4*)&VT[((size_t)((b * 16 + h) * 64 + d)) * 2048 + n_base + m2 * 16] = pv;
      }
  } else {
#pragma unroll
    for (int m2 = 0; m2 < 2; ++m2)
#pragma unroll
      for (int nt = 0; nt < 4; ++nt) {
        int col = n0 + wc * 64 + nt * 16 + c;
#pragma unroll
        for (int r = 0; r < 4; ++r)
          Co[(size_t)(m0 + wr * 32 + m2 * 16 + g * 4 + r) * 1024 + col] =
              (f16)acc[m2][nt][r];
      }
  }
}

// ----------------------------- proj GEMM 64x64, split-K=2, atomic epilogue
// 1024 blocks; bias pre-written to C by combine_kernel.
__global__ __launch_bounds__(256) void proj_gemm_kernel(
    const f16* __restrict__ A, const f16* __restrict__ Bw,
    float* __restrict__ C) {
  __shared__ __align__(16) f16 As[2][64 * 64];
  __shared__ __align__(16) f16 Bs[2][64 * 64];
  const int bid = blockIdx.x;
  const int swz = (bid & 7) * 128 + (bid >> 3);
  const int n0 = (swz & 15) * 64, m0 = ((swz >> 4) & 31) * 64;
  const int kbase = (swz >> 9) * 512;
  const int tid = threadIdx.x, lane = tid & 63, w = tid >> 6;
  const int wr = w >> 1, wc = w & 1, g = lane >> 4, c = lane & 15;
  const int r_st = tid >> 3, t_st = tid & 7;

  auto stage = [&](int k0, int buf) {
#pragma unroll
    for (int i = 0; i < 2; ++i) {
      int row = r_st + i * 32;
      int sl = (t_st ^ (row & 7)) * 8;
      gld16(&A[(size_t)(m0 + row) * 1024 + k0 + sl], &As[buf][(row * 8 + t_st) * 8]);
      gld16(&Bw[(size_t)(n0 + row) * 1024 + k0 + sl], &Bs[buf][(row * 8 + t_st) * 8]);
    }
  };

  f32x4 acc[2][2] = {};

  stage(kbase, 0);
  __syncthreads();

  for (int t = 0; t < 8; ++t) {
    const int cur = t & 1;
    if (t < 7) stage(kbase + (t + 1) * 64, cur ^ 1);
#pragma unroll
    for (int kb = 0; kb < 2; ++kb) {
      f16x8 af[2], bf[2];
      const int sw = ((kb * 4 + g) ^ (c & 7)) * 8;
#pragma unroll
      for (int m2 = 0; m2 < 2; ++m2)
        af[m2] = *(const f16x8*)&As[cur][(wr * 32 + m2 * 16 + c) * 64 + sw];
#pragma unroll
      for (int nt = 0; nt < 2; ++nt)
        bf[nt] = *(const f16x8*)&Bs[cur][(wc * 32 + nt * 16 + c) * 64 + sw];
#pragma unroll
      for (int m2 = 0; m2 < 2; ++m2)
#pragma unroll
        for (int nt = 0; nt < 2; ++nt)
          acc[m2][nt] = MFMA_F16(af[m2], bf[nt], acc[m2][nt]);
    }
    __syncthreads();
  }

#pragma unroll
  for (int m2 = 0; m2 < 2; ++m2)
#pragma unroll
    for (int nt = 0; nt < 2; ++nt) {
      int col = n0 + wc * 32 + nt * 16 + c;
#pragma unroll
      for (int r = 0; r < 4; ++r)
        unsafeAtomicAdd(&C[(size_t)(m0 + wr * 32 + m2 * 16 + g * 4 + r) * 1024 + col],
                        acc[m2][nt][r]);
    }
}

// -------------------------------------------------------------- attention
// R5 fat-wave version (proven 39.8us) + s_setprio around MFMA clusters (T5).
__global__ __launch_bounds__(256, 3) void attn_kernel(const f16* __restrict__ Q,
                                                      const f16* __restrict__ Kg,
                                                      const f16* __restrict__ VT,
                                                      f16* __restrict__ Opart,
                                                      float* __restrict__ ML) {
  __shared__ __align__(16) f16 Ks[2][64 * 64];
  __shared__ __align__(16) f16 Vs[64 * 64];
  __shared__ __align__(16) f16 Ps[4][32 * 64];
  const int flat = blockIdx.x;
  const int swz = (flat & 7) * 128 + (flat >> 3);
  const int qt = swz & 7, h = (swz >> 3) & 15;
  const int ch = (swz >> 7) & 3, b = swz >> 9;
  const int tid = threadIdx.x, lane = tid & 63, w = tid >> 6;
  const int g = lane >> 4, c = lane & 15;
  const int r_st = tid >> 3, t_st = tid & 7;

  const f16* Kbase = Kg + (size_t)(b * 2048 + ch * 512) * 1024 + h * 64;
  const f16* Vbase = VT + ((size_t)((b * 16 + h) * 64)) * 2048 + ch * 512;

  f16x8 qf[2][2];
#pragma unroll
  for (int qs = 0; qs < 2; ++qs) {
    const f16* qp =
        Q + (size_t)(b * 2048 + qt * 128 + w * 32 + qs * 16 + c) * 1024 + h * 64;
    qf[qs][0] = *(const f16x8*)(qp + g * 8);
    qf[qs][1] = *(const f16x8*)(qp + 32 + g * 8);
#pragma unroll
    for (int j = 0; j < 8; ++j) {
      qf[qs][0][j] = (f16)((float)qf[qs][0][j] * 0.1803368801f);
      qf[qs][1][j] = (f16)((float)qf[qs][1][j] * 0.1803368801f);
    }
  }

  auto stageK = [&](int t, int buf) {
#pragma unroll
    for (int i = 0; i < 2; ++i) {
      int row = r_st + i * 32;
      int sl = (t_st ^ (row & 7)) * 8;
      gld16(&Kbase[(size_t)(t * 64 + row) * 1024 + sl],
            &Ks[buf][(row * 8 + t_st) * 8]);
    }
  };
  auto stageV = [&](int t) {
#pragma unroll
    for (int i = 0; i < 2; ++i) {
      int row = r_st + i * 32;
      int sl = (t_st ^ (row & 7)) * 8;
      gld16(&Vbase[(size_t)row * 2048 + t * 64 + sl], &Vs[(row * 8 + t_st) * 8]);
    }
  };

  f32x4 oaccT[4][2] = {};
  float l_part[2] = {0.f, 0.f};

  stageK(0, 0);
  stageV(0);
  asm volatile("s_waitcnt vmcnt(0)" ::: "memory");
  __builtin_amdgcn_s_barrier();
  __builtin_amdgcn_sched_barrier(0);

  for (int t = 0; t < 8; ++t) {
    const int cur = t & 1;
    if (t < 7) stageK(t + 1, cur ^ 1);

#pragma unroll
    for (int qs = 0; qs < 2; ++qs) {
      f32x4 s[4] = {};
      __builtin_amdgcn_s_setprio(1);
#pragma unroll
      for (int kt = 0; kt < 4; ++kt) {
        f16x8 kf0 =
            *(const f16x8*)&Ks[cur][(kt * 16 + c) * 64 + ((g ^ (c & 7)) * 8)];
        f16x8 kf1 =
            *(const f16x8*)&Ks[cur][(kt * 16 + c) * 64 + (((4 + g) ^ (c & 7)) * 8)];
        s[kt] = MFMA_F16(kf0, qf[qs][0], s[kt]);
        s[kt] = MFMA_F16(kf1, qf[qs][1], s[kt]);
      }
      __builtin_amdgcn_s_setprio(0);
      float rs = 0.f;
#pragma unroll
      for (int kt = 0; kt < 4; ++kt)
#pragma unroll
        for (int r = 0; r < 4; ++r) {
          float p = exp2f(s[kt][r]);
          s[kt][r] = p;
          rs += p;
        }
      l_part[qs] += rs;
#pragma unroll
      for (int kt = 0; kt < 4; ++kt) {
        f16x4 pv = {(f16)s[kt][0], (f16)s[kt][1], (f16)s[kt][2], (f16)s[kt][3]};
        *(f16x4*)&Ps[w][(qs * 16 + c) * 64 +
                        (((kt * 2 + (g >> 1)) ^ (c & 7)) * 8) + (g & 1) * 4] = pv;
      }
    }

    if (t < 7) {
      asm volatile("s_waitcnt vmcnt(2)" ::: "memory");
    } else {
      asm volatile("s_waitcnt vmcnt(0)" ::: "memory");
    }
    __builtin_amdgcn_s_barrier();
    __builtin_amdgcn_sched_barrier(0);

    __builtin_amdgcn_s_setprio(1);
#pragma unroll
    for (int kb = 0; kb < 2; ++kb) {
      f16x8 pf0 =
          *(const f16x8*)&Ps[w][c * 64 + (((kb * 4 + g) ^ (c & 7)) * 8)];
      f16x8 pf1 =
          *(const f16x8*)&Ps[w][(16 + c) * 64 + (((kb * 4 + g) ^ (c & 7)) * 8)];
#pragma unroll
      for (int dt = 0; dt < 4; ++dt) {
        f16x8 vf = *(const f16x8*)&Vs[(dt * 16 + c) * 64 +
                                      (((kb * 4 + g) ^ (c & 7)) * 8)];
        oaccT[dt][0] = MFMA_F16(vf, pf0, oaccT[dt][0]);
        oaccT[dt][1] = MFMA_F16(vf, pf1, oaccT[dt][1]);
      }
    }
    __builtin_amdgcn_s_setprio(0);

    asm volatile("s_waitcnt vmcnt(0)" ::: "memory");
    __builtin_amdgcn_s_barrier();
    __builtin_amdgcn_sched_barrier(0);
    if (t < 7) stageV(t + 1);
  }

  float lf[2];
#pragma unroll
  for (int qs = 0; qs < 2; ++qs) {
    float l = l_part[qs];
    l += __shfl_xor(l, 16);
    l += __shfl_xor(l, 32);
    lf[qs] = l;
  }
#pragma unroll
  for (int qs = 0; qs < 2; ++qs) {
    float li = 1.f / lf[qs];
#pragma unroll
    for (int dt = 0; dt < 4; ++dt) {
      f16x4 ov = {(f16)(oaccT[dt][qs][0] * li), (f16)(oaccT[dt][qs][1] * li),
                  (f16)(oaccT[dt][qs][2] * li), (f16)(oaccT[dt][qs][3] * li)};
      *(f16x4*)&Opart[(size_t)ch * 2097152 +
                      (size_t)(b * 1024 + qt * 128 + w * 32 + qs * 16 + c) * 1024 +
                      h * 64 + dt * 16 + g * 4] = ov;
    }
  }
  if (lane < 16) {
#pragma unroll
    for (int qs = 0; qs < 2; ++qs)
      ML[ch * 32768 + (b * 1024 + qt * 128 + w * 32 + qs * 16 + lane) * 16 + h] =
          lf[qs];
  }
}

// ------------------------------------- combine (4 chunks) + bias preset for proj
__global__ __launch_bounds__(256) void combine_kernel(const f16* __restrict__ Opart,
                                                      const float* __restrict__ ML,
                                                      f16* __restrict__ O16,
                                                      float* __restrict__ outp,
                                                      const float* __restrict__ bias) {
  int i = blockIdx.x * 256 + threadIdx.x;  // 262144 groups of 8
  int row = i >> 7;
  int h = (i & 127) >> 3;
  float l0 = ML[row * 16 + h];
  float l1 = ML[32768 + row * 16 + h];
  float l2 = ML[65536 + row * 16 + h];
  float l3 = ML[98304 + row * 16 + h];
  float inv = 1.f / (l0 + l1 + l2 + l3);
  f16x8 o0 = *(const f16x8*)&Opart[(size_t)i * 8];
  f16x8 o1 = *(const f16x8*)&Opart[2097152 + (size_t)i * 8];
  f16x8 o2 = *(const f16x8*)&Opart[4194304 + (size_t)i * 8];
  f16x8 o3 = *(const f16x8*)&Opart[6291456 + (size_t)i * 8];
  f16x8 r;
#pragma unroll
  for (int j = 0; j < 8; ++j)
    r[j] = (f16)((l0 * (float)o0[j] + l1 * (float)o1[j] + l2 * (float)o2[j] +
                  l3 * (float)o3[j]) * inv);
  *(f16x8*)&O16[(size_t)i * 8] = r;
  // preset proj output with bias (proj accumulates atomically on top)
  int cb = (i & 127) * 8;
#pragma unroll
  for (int j = 0; j < 8; ++j) outp[(size_t)i * 8 + j] = bias[cb + j];
}

// ---------------------------------------------------------------- launcher
extern "C" void kernel_launch(void* const* d_in, const int* in_sizes, int n_in,
                              void* d_out, int out_size, void* d_ws, size_t ws_size,
                              hipStream_t stream) {
  const float* x = (const float*)d_in[0];
  const float* wq = (const float*)d_in[1];
  const float* wk = (const float*)d_in[2];
  const float* wv = (const float*)d_in[3];
  const float* wp = (const float*)d_in[4];
  const float* bp = (const float*)d_in[5];
  float* out = (float*)d_out;

  char* p = (char*)d_ws;
  f16* x16 = (f16*)p;   p += (size_t)4194304 * 2;      // ML aliases after GEMMs
  f16* w16 = (f16*)p;   p += (size_t)4 * 1048576 * 2;
  f16* Q16 = (f16*)p;   p += (size_t)4194304 * 2;
  f16* K16 = (f16*)p;   p += (size_t)4194304 * 2;
  f16* VT16 = (f16*)p;  p += (size_t)4194304 * 2;      // [B,H,D,N]
  f16* Opart = (f16*)p; p += (size_t)8388608 * 2;      // 4 chunks x [B*Nq, C]
  f16* O16 = (f16*)p;   p += (size_t)2097152 * 2;

  f16* wq16 = w16;
  f16* wk16 = w16 + 1048576;
  f16* wv16 = w16 + 2 * 1048576;
  f16* wp16 = w16 + 3 * 1048576;

  cvt_x_kernel<<<4194304 / 8 / 256, 256, 0, stream>>>(x, x16, 4194304 / 8);
  cvt_w4_kernel<<<4 * 131072 / 256, 256, 0, stream>>>(wq, wk, wv, wp, w16);

  qkv_gemm_kernel<<<dim3(8, 160), 256, 0, stream>>>(x16, wq16, wk16, wv16, Q16, K16,
                                                    VT16);

  float* MLp = (float*)x16;
  attn_kernel<<<dim3(1024), 256, 0, stream>>>(Q16, K16, VT16, Opart, MLp);
  combine_kernel<<<1024, 256, 0, stream>>>(Opart, MLp, O16, out, bp);

  proj_gemm_kernel<<<dim3(1024), 256, 0, stream>>>(O16, wp16, out);
}